// Round 1
// baseline (3011.258 us; speedup 1.0000x reference)
//
#include <hip/hip_runtime.h>
#include <math.h>

// Problem constants: B=8, N=1024, D=256, R=2, P=256, HOPS=3
#define Bn 8
#define Nn 1024
#define Dn 256
#define Rn 2
#define Pn 256
#define SCALE 0.0625f
#define NEGF -3.0e38f

// Workspace requirement: ~77 MB of fp32 (cur1,cur2,q,nb/update,agg,su,Wpack,bpack)

// ---------------- pack weights: Wp[256][1280] = [Wa0|Wa1|Wr0|Wr1|Ws], bp[1280]
__global__ void pack_w(const float* __restrict__ Wa, const float* __restrict__ Wr,
                       const float* __restrict__ br, const float* __restrict__ Ws,
                       const float* __restrict__ bs, float* __restrict__ Wp,
                       float* __restrict__ bp) {
  int j = blockIdx.x * 256 + threadIdx.x;  // 0..1279
  for (int d = 0; d < 256; ++d) {
    float v;
    if (j < 512)       v = Wa[((j >> 8) * 256 + d) * 256 + (j & 255)];
    else if (j < 1024) v = Wr[(((j - 512) >> 8) * 256 + d) * 256 + (j & 255)];
    else               v = Ws[d * 256 + (j - 1024)];
    Wp[d * 1280 + j] = v;
  }
  float bv = 0.f;
  if (j >= 512 && j < 1024) bv = br[((j - 512) >> 8) * 256 + (j & 255)];
  else if (j >= 1024)       bv = bs[j - 1024];
  bp[j] = bv;
}

// ---------------- proj: C[8192,1280] = cur[8192,256] @ Wp, scatter to q/nb/su
__global__ __launch_bounds__(256) void proj_gemm(
    const float* __restrict__ cur, const float* __restrict__ Wp,
    const float* __restrict__ bp, const float* __restrict__ mask,
    float* __restrict__ q, float* __restrict__ nb, float* __restrict__ su) {
  __shared__ float As[16][68];
  __shared__ float Bs[16][68];
  int tid = threadIdx.x;
  int rm = blockIdx.x * 64, cn = blockIdx.y * 64;
  int tx = tid & 15, ty = tid >> 4;
  int la_c = tid & 15, la_r = tid >> 4;
  int lb_c = tid & 63, lb_r = tid >> 6;
  float acc[4][4] = {};
  for (int k0 = 0; k0 < 256; k0 += 16) {
#pragma unroll
    for (int rr = 0; rr < 4; ++rr)
      As[la_c][la_r + rr * 16] = cur[(size_t)(rm + la_r + rr * 16) * 256 + k0 + la_c];
#pragma unroll
    for (int rr = 0; rr < 4; ++rr)
      Bs[lb_r + rr * 4][lb_c] = Wp[(size_t)(k0 + lb_r + rr * 4) * 1280 + cn + lb_c];
    __syncthreads();
#pragma unroll
    for (int kk = 0; kk < 16; ++kk) {
      float a[4], bb[4];
#pragma unroll
      for (int i = 0; i < 4; ++i) a[i] = As[kk][ty * 4 + i];
#pragma unroll
      for (int j = 0; j < 4; ++j) bb[j] = Bs[kk][tx * 4 + j];
#pragma unroll
      for (int i = 0; i < 4; ++i)
#pragma unroll
        for (int j = 0; j < 4; ++j) acc[i][j] += a[i] * bb[j];
    }
    __syncthreads();
  }
#pragma unroll
  for (int i = 0; i < 4; ++i) {
    int row = rm + ty * 4 + i;
    int b = row >> 10, n = row & 1023;
    float mk = mask[row];
#pragma unroll
    for (int j = 0; j < 4; ++j) {
      int col = cn + tx * 4 + j;
      float v = acc[i][j];
      if (col < 512) {
        int r = col >> 8, e = col & 255;
        q[(((size_t)(b * 2 + r) << 10) + n) * 256 + e] = v;
      } else if (col < 1024) {
        int r = (col >> 8) - 2, e = col & 255;
        nb[(((size_t)(b * 2 + r) << 10) + n) * 256 + e] = (v + bp[col]) * mk;
      } else {
        su[(size_t)row * 256 + (col - 1024)] = (v + bp[col]) * mk;
      }
    }
  }
}

// ---------------- agg[b,r] = adj[b,r][1024,1024] @ nb[b,r][1024,256]
__global__ __launch_bounds__(256) void agg_gemm(
    const float* __restrict__ adj, const float* __restrict__ nb,
    float* __restrict__ agg) {
  __shared__ float As[16][68];
  __shared__ float Bs[16][68];
  int z = blockIdx.z;  // b*R + r
  const float* A = adj + (size_t)z * Nn * Nn;
  const float* Bm = nb + (size_t)z * Nn * Pn;
  float* C = agg + (size_t)z * Nn * Pn;
  int tid = threadIdx.x;
  int rm = blockIdx.x * 64, cn = blockIdx.y * 64;
  int tx = tid & 15, ty = tid >> 4;
  int la_c = tid & 15, la_r = tid >> 4;
  int lb_c = tid & 63, lb_r = tid >> 6;
  float acc[4][4] = {};
  for (int k0 = 0; k0 < 1024; k0 += 16) {
#pragma unroll
    for (int rr = 0; rr < 4; ++rr)
      As[la_c][la_r + rr * 16] = A[(size_t)(rm + la_r + rr * 16) * 1024 + k0 + la_c];
#pragma unroll
    for (int rr = 0; rr < 4; ++rr)
      Bs[lb_r + rr * 4][lb_c] = Bm[(size_t)(k0 + lb_r + rr * 4) * 256 + cn + lb_c];
    __syncthreads();
#pragma unroll
    for (int kk = 0; kk < 16; ++kk) {
      float a[4], bb[4];
#pragma unroll
      for (int i = 0; i < 4; ++i) a[i] = As[kk][ty * 4 + i];
#pragma unroll
      for (int j = 0; j < 4; ++j) bb[j] = Bs[kk][tx * 4 + j];
#pragma unroll
      for (int i = 0; i < 4; ++i)
#pragma unroll
        for (int j = 0; j < 4; ++j) acc[i][j] += a[i] * bb[j];
    }
    __syncthreads();
  }
#pragma unroll
  for (int i = 0; i < 4; ++i)
#pragma unroll
    for (int j = 0; j < 4; ++j)
      C[(size_t)(rm + ty * 4 + i) * 256 + cn + tx * 4 + j] = acc[i][j];
}

// ---------------- flash attention + update accumulation over r, + su
// 16 rows per block, m-tiles of 64. up[b,n,p] = sum_r softmax(adj-masked qk)@agg + su
__global__ __launch_bounds__(256) void flash_attn(
    const float* __restrict__ q, const float* __restrict__ cur,
    const float* __restrict__ adj, const float* __restrict__ agg,
    const float* __restrict__ su, float* __restrict__ up) {
  __shared__ float Qs[16][20];
  __shared__ float Cs[16][68];
  __shared__ float Ps[16][68];
  __shared__ float AggS[16][260];
  int b = blockIdx.y;
  int rm = blockIdx.x * 16;
  int tid = threadIdx.x;
  int tx = tid & 15, ty = tid >> 4;
  int qc = tid & 15, qr = tid >> 4;
  int ac = tid & 63, ar = tid >> 6;
  float U[16];
#pragma unroll
  for (int c = 0; c < 16; ++c) U[c] = 0.f;
  for (int r = 0; r < Rn; ++r) {
    const float* qb   = q   + (size_t)(b * Rn + r) * Nn * Dn;
    const float* adjb = adj + (size_t)(b * Rn + r) * Nn * Nn;
    const float* aggb = agg + (size_t)(b * Rn + r) * Nn * Pn;
    float O[16];
#pragma unroll
    for (int c = 0; c < 16; ++c) O[c] = 0.f;
    float mrow = NEGF, lrow = 0.f;
    for (int mt = 0; mt < Nn; mt += 64) {
      // S[16 rows][64 m] = q_tile @ cur_tile^T
      float S[4] = {0.f, 0.f, 0.f, 0.f};
      for (int k0 = 0; k0 < Dn; k0 += 16) {
        Qs[qc][qr] = qb[(size_t)(rm + qr) * Dn + k0 + qc];
#pragma unroll
        for (int rr = 0; rr < 4; ++rr)
          Cs[qc][qr + rr * 16] =
              cur[((size_t)b * Nn + mt + qr + rr * 16) * Dn + k0 + qc];
        __syncthreads();
#pragma unroll
        for (int kk = 0; kk < 16; ++kk) {
          float a = Qs[kk][ty];
#pragma unroll
          for (int j = 0; j < 4; ++j) S[j] += a * Cs[kk][tx * 4 + j];
        }
        __syncthreads();
      }
      // mask + scale + online softmax stats (row = rm+ty, 16 tx threads per row)
      int rowg = rm + ty;
      float tmax = NEGF;
#pragma unroll
      for (int j = 0; j < 4; ++j) {
        float av = adjb[(size_t)rowg * Nn + mt + tx * 4 + j];
        float s = S[j] * SCALE;
        S[j] = (av > 0.f) ? s : NEGF;
        tmax = fmaxf(tmax, S[j]);
      }
#pragma unroll
      for (int off = 1; off < 16; off <<= 1)
        tmax = fmaxf(tmax, __shfl_xor(tmax, off));
      float mnew = fmaxf(mrow, tmax);
      float corr = expf(mrow - mnew);  // both NEGF -> exp(0)=1; NEGF-finite -> 0
      float p[4];
      float psum = 0.f;
#pragma unroll
      for (int j = 0; j < 4; ++j) {
        p[j] = (S[j] > -1.0e38f) ? expf(S[j] - mnew) : 0.f;
        psum += p[j];
      }
#pragma unroll
      for (int off = 1; off < 16; off <<= 1) psum += __shfl_xor(psum, off);
      mrow = mnew;
      lrow = lrow * corr + psum;
#pragma unroll
      for (int c = 0; c < 16; ++c) O[c] *= corr;
#pragma unroll
      for (int j = 0; j < 4; ++j) Ps[ty][tx * 4 + j] = p[j];
      __syncthreads();
      // O += Ps[16][64] @ agg[mt:mt+64][256]
      for (int k0 = 0; k0 < 64; k0 += 16) {
#pragma unroll
        for (int rr = 0; rr < 4; ++rr)
#pragma unroll
          for (int cc2 = 0; cc2 < 4; ++cc2)
            AggS[ar + rr * 4][ac + cc2 * 64] =
                aggb[(size_t)(mt + k0 + ar + rr * 4) * Pn + ac + cc2 * 64];
        __syncthreads();
#pragma unroll
        for (int kk = 0; kk < 16; ++kk) {
          float pv = Ps[ty][k0 + kk];
#pragma unroll
          for (int cc = 0; cc < 16; ++cc) O[cc] += pv * AggS[kk][cc * 16 + tx];
        }
        __syncthreads();
      }
    }
    float rcp = (lrow > 0.f) ? 1.f / lrow : 0.f;
#pragma unroll
    for (int cc = 0; cc < 16; ++cc) U[cc] += O[cc] * rcp;
  }
  int rowg = rm + ty;
  size_t baseo = ((size_t)b * Nn + rowg) * Pn;
#pragma unroll
  for (int cc = 0; cc < 16; ++cc) {
    int col = cc * 16 + tx;
    up[baseo + col] = U[cc] + su[baseo + col];
  }
}

// ---------------- gate: v = [up|cin] @ Wg + bg; g = sigmoid(v)*mask;
//                   cout = g*tanh(up) + (1-g)*cin
__global__ __launch_bounds__(256) void gate_gemm(
    const float* __restrict__ up, const float* __restrict__ cin,
    const float* __restrict__ Wg, const float* __restrict__ bg,
    const float* __restrict__ mask, float* __restrict__ cout) {
  __shared__ float As[16][68];
  __shared__ float Bs[16][68];
  int tid = threadIdx.x;
  int rm = blockIdx.x * 64, cn = blockIdx.y * 64;
  int tx = tid & 15, ty = tid >> 4;
  int la_c = tid & 15, la_r = tid >> 4;
  int lb_c = tid & 63, lb_r = tid >> 6;
  float acc[4][4] = {};
  for (int k0 = 0; k0 < 512; k0 += 16) {
    int k = k0 + la_c;
    const float* Asrc = (k < 256) ? up : cin;
    int kc = k & 255;
#pragma unroll
    for (int rr = 0; rr < 4; ++rr)
      As[la_c][la_r + rr * 16] = Asrc[(size_t)(rm + la_r + rr * 16) * 256 + kc];
#pragma unroll
    for (int rr = 0; rr < 4; ++rr)
      Bs[lb_r + rr * 4][lb_c] = Wg[(size_t)(k0 + lb_r + rr * 4) * 256 + cn + lb_c];
    __syncthreads();
#pragma unroll
    for (int kk = 0; kk < 16; ++kk) {
      float a[4], bb[4];
#pragma unroll
      for (int i = 0; i < 4; ++i) a[i] = As[kk][ty * 4 + i];
#pragma unroll
      for (int j = 0; j < 4; ++j) bb[j] = Bs[kk][tx * 4 + j];
#pragma unroll
      for (int i = 0; i < 4; ++i)
#pragma unroll
        for (int j = 0; j < 4; ++j) acc[i][j] += a[i] * bb[j];
    }
    __syncthreads();
  }
#pragma unroll
  for (int i = 0; i < 4; ++i) {
    int row = rm + ty * 4 + i;
    float mk = mask[row];
#pragma unroll
    for (int j = 0; j < 4; ++j) {
      int col = cn + tx * 4 + j;
      float v = acc[i][j] + bg[col];
      float g = mk / (1.f + expf(-v));
      size_t idx = (size_t)row * 256 + col;
      float u = up[idx];
      float c0 = cin[idx];
      cout[idx] = g * tanhf(u) + (1.f - g) * c0;
    }
  }
}

extern "C" void kernel_launch(void* const* d_in, const int* in_sizes, int n_in,
                              void* d_out, int out_size, void* d_ws, size_t ws_size,
                              hipStream_t stream) {
  const float* x    = (const float*)d_in[0];
  const float* mask = (const float*)d_in[1];
  const float* adj  = (const float*)d_in[2];
  const float* Wa   = (const float*)d_in[3];
  const float* Wr   = (const float*)d_in[4];
  const float* br   = (const float*)d_in[5];
  const float* Ws   = (const float*)d_in[6];
  const float* bs   = (const float*)d_in[7];
  const float* Wg   = (const float*)d_in[8];
  const float* bg   = (const float*)d_in[9];
  float* out = (float*)d_out;
  float* ws = (float*)d_ws;

  float* cur1 = ws;                                  // B*N*D
  float* cur2 = cur1 + (size_t)Bn * Nn * Dn;         // B*N*D
  float* qbuf = cur2 + (size_t)Bn * Nn * Dn;         // B*R*N*D
  float* nbuf = qbuf + (size_t)Bn * Rn * Nn * Dn;    // B*R*N*P (nb, then update)
  float* abuf = nbuf + (size_t)Bn * Rn * Nn * Pn;    // B*R*N*P (agg)
  float* sbuf = abuf + (size_t)Bn * Rn * Nn * Pn;    // B*N*P   (su)
  float* wp   = sbuf + (size_t)Bn * Nn * Pn;         // 256*1280
  float* bp   = wp + 256 * 1280;                     // 1280

  pack_w<<<dim3(5), dim3(256), 0, stream>>>(Wa, Wr, br, Ws, bs, wp, bp);
  for (int h = 0; h < 3; ++h) {
    const float* cin = (h == 0) ? x : ((h == 1) ? cur1 : cur2);
    float* cout = (h == 0) ? cur1 : ((h == 1) ? cur2 : out);
    proj_gemm<<<dim3(128, 20), dim3(256), 0, stream>>>(cin, wp, bp, mask, qbuf, nbuf, sbuf);
    agg_gemm<<<dim3(16, 4, 16), dim3(256), 0, stream>>>(adj, nbuf, abuf);
    flash_attn<<<dim3(64, 8), dim3(256), 0, stream>>>(qbuf, cin, adj, abuf, sbuf, nbuf);
    gate_gemm<<<dim3(128, 4), dim3(256), 0, stream>>>(nbuf, cin, Wg, bg, mask, cout);
  }
}